// Round 1
// 506.362 us; speedup vs baseline: 1.0079x; 1.0079x over previous
//
#include <hip/hip_runtime.h>

// MultisenseLearner: out[b] = logsumexp_{s,t}( sum_d W[j,d,s]*V[i,d,t] + wb[j,s] + vb[i,t] )
// V,W: (50000,300,4) f32; vb,wb: (50000,4) f32; IJ: (100000,2) int; out: (100000,) f32.
//
// R3 change vs R2/R2.5: the compiler had re-serialized the 10 row-gather float4
// loads (VGPR_Count=32 proves it -- 10 live float4 need 40 VGPRs), leaving the
// kernel latency-bound at 2.6 TB/s. Now a __builtin_amdgcn_sched_barrier(0)
// fence pins ALL loads (10x float4 + 2 bias) before any FMA, so each wave does
// one memory round-trip with 10KB in flight instead of ~5 serialized trips.
// Also: int64-vs-int32 layout resolved on HOST from in_sizes[4] (bytes), which
// deletes the per-wave probe-load->ballot dependency from the critical path
// (device probe kept only as mode==0 fallback). Tail mask-multiply moved after
// the fence so it can't force vmcnt(0) before the first FMA.

constexpr int D   = 300;
constexpr int NS  = 4;
constexpr int ROW = D * NS;   // 1200 floats per gathered row

__global__ __launch_bounds__(256) void multisense_kernel(
    const float* __restrict__ V,
    const float* __restrict__ W,
    const float* __restrict__ vb,
    const float* __restrict__ wb,
    const unsigned int* __restrict__ IJw,   // raw 32-bit view of IJ
    float* __restrict__ out,
    int B,
    int mode)                               // 1 = int64 data, 2 = int32 data, 0 = probe on device
{
    const int lane = threadIdx.x & 63;
    const int b    = blockIdx.x * (blockDim.x >> 6) + (threadIdx.x >> 6);
    if (b >= B) return;   // whole wave uniform

    int i, j;
    if (mode == 1)      { i = (int)IJw[4 * (size_t)b]; j = (int)IJw[4 * (size_t)b + 2]; }
    else if (mode == 2) { i = (int)IJw[2 * (size_t)b]; j = (int)IJw[2 * (size_t)b + 1]; }
    else {
        // Fallback: indices < 50000 < 2^31, so int64 data has every odd 32-bit
        // word == 0. P(int32 data aliasing) ~ (2e-5)^32 ~ 0.
        unsigned int probe = (lane < 32) ? IJw[2 * lane + 1] : 0u;
        const bool isI64 = (__ballot(probe != 0u) == 0ull);
        if (isI64) { i = (int)IJw[4 * (size_t)b]; j = (int)IJw[4 * (size_t)b + 2]; }
        else       { i = (int)IJw[2 * (size_t)b]; j = (int)IJw[2 * (size_t)b + 1]; }
    }

    const float* __restrict__ Vr = V + (size_t)i * ROW;
    const float* __restrict__ Wr = W + (size_t)j * ROW;

    // Epilogue ownership: after the splitting reduction, lane holds the full
    // d-sum for sense pair m = (lane>>2)&15, i.e. s=(lane>>4)&3, t=(lane>>2)&3.
    const int s_idx = (lane >> 4) & 3;
    const int t_idx = (lane >> 2) & 3;

    // ---- LOAD REGION: issue ALL memory ops, nothing consumes them here ----
    const float wbj = wb[(size_t)j * NS + s_idx];
    const float vbi = vb[(size_t)i * NS + t_idx];

    // tail lane d = 256+lane is valid only for lanes 0..43 (D=300): clamp the
    // address in-row; the zeroing multiply happens AFTER the fence.
    const int   d4 = 256 + lane;
    const int   dc = (d4 < D) ? d4 : 0;
    const float m  = (d4 < D) ? 1.0f : 0.0f;

    float4 va[5], wa[5];
#pragma unroll
    for (int k = 0; k < 4; ++k) {
        const int d = lane + 64 * k;
        va[k] = *reinterpret_cast<const float4*>(Vr + (size_t)d * NS);
        wa[k] = *reinterpret_cast<const float4*>(Wr + (size_t)d * NS);
    }
    va[4] = *reinterpret_cast<const float4*>(Vr + (size_t)dc * NS);
    wa[4] = *reinterpret_cast<const float4*>(Wr + (size_t)dc * NS);

    // Scheduling fence: no instruction may cross. Loads above cannot be sunk
    // into the FMA block below -> all 10 gathers stay in flight together.
    __builtin_amdgcn_sched_barrier(0);

    // ---- COMPUTE REGION: 4x4 Gram accumulation, f32 ----
    // k=0 initializes acc via muls (no zero-init; acc lifetimes start here).
    float acc[16];
    {
        const float v0 = va[0].x, v1 = va[0].y, v2 = va[0].z, v3 = va[0].w;
        const float w0 = wa[0].x, w1 = wa[0].y, w2 = wa[0].z, w3 = wa[0].w;
        acc[ 0] = w0 * v0; acc[ 1] = w0 * v1; acc[ 2] = w0 * v2; acc[ 3] = w0 * v3;
        acc[ 4] = w1 * v0; acc[ 5] = w1 * v1; acc[ 6] = w1 * v2; acc[ 7] = w1 * v3;
        acc[ 8] = w2 * v0; acc[ 9] = w2 * v1; acc[10] = w2 * v2; acc[11] = w2 * v3;
        acc[12] = w3 * v0; acc[13] = w3 * v1; acc[14] = w3 * v2; acc[15] = w3 * v3;
    }
#pragma unroll
    for (int k = 1; k < 5; ++k) {
        float4 vv = va[k];
        float4 ww = wa[k];
        if (k == 4) {   // compile-time: zero the invalid-tail contribution
            ww.x *= m; ww.y *= m; ww.z *= m; ww.w *= m;
        }
        const float v0 = vv.x, v1 = vv.y, v2 = vv.z, v3 = vv.w;
        const float w0 = ww.x, w1 = ww.y, w2 = ww.z, w3 = ww.w;
        acc[ 0] = fmaf(w0, v0, acc[ 0]); acc[ 1] = fmaf(w0, v1, acc[ 1]);
        acc[ 2] = fmaf(w0, v2, acc[ 2]); acc[ 3] = fmaf(w0, v3, acc[ 3]);
        acc[ 4] = fmaf(w1, v0, acc[ 4]); acc[ 5] = fmaf(w1, v1, acc[ 5]);
        acc[ 6] = fmaf(w1, v2, acc[ 6]); acc[ 7] = fmaf(w1, v3, acc[ 7]);
        acc[ 8] = fmaf(w2, v0, acc[ 8]); acc[ 9] = fmaf(w2, v1, acc[ 9]);
        acc[10] = fmaf(w2, v2, acc[10]); acc[11] = fmaf(w2, v3, acc[11]);
        acc[12] = fmaf(w3, v0, acc[12]); acc[13] = fmaf(w3, v1, acc[13]);
        acc[14] = fmaf(w3, v2, acc[14]); acc[15] = fmaf(w3, v3, acc[15]);
    }

    // ---- value-splitting wave reduction: 16 vals -> 1 val/lane in 4 steps ----
    const bool b5 = (lane & 32) != 0;
    float r8[8];
#pragma unroll
    for (int mm = 0; mm < 8; ++mm) {
        const float send = b5 ? acc[mm]     : acc[mm + 8];
        const float keep = b5 ? acc[mm + 8] : acc[mm];
        r8[mm] = keep + __shfl_xor(send, 32, 64);
    }
    const bool b4 = (lane & 16) != 0;
    float r4[4];
#pragma unroll
    for (int mm = 0; mm < 4; ++mm) {
        const float send = b4 ? r8[mm]     : r8[mm + 4];
        const float keep = b4 ? r8[mm + 4] : r8[mm];
        r4[mm] = keep + __shfl_xor(send, 16, 64);
    }
    const bool b3 = (lane & 8) != 0;
    float r2[2];
#pragma unroll
    for (int mm = 0; mm < 2; ++mm) {
        const float send = b3 ? r4[mm]     : r4[mm + 2];
        const float keep = b3 ? r4[mm + 2] : r4[mm];
        r2[mm] = keep + __shfl_xor(send, 8, 64);
    }
    const bool b2 = (lane & 4) != 0;
    float r1;
    {
        const float send = b2 ? r2[0] : r2[1];
        const float keep = b2 ? r2[1] : r2[0];
        r1 = keep + __shfl_xor(send, 4, 64);
    }
    // finish the d-sum across lane bits 1:0 (same sense-pair class)
    r1 += __shfl_xor(r1, 2, 64);
    r1 += __shfl_xor(r1, 1, 64);

    // ---- epilogue: one exp per lane, reduce 16 distinct classes ----
    float e = expf(r1 + wbj + vbi);
    e += __shfl_xor(e,  4, 64);
    e += __shfl_xor(e,  8, 64);
    e += __shfl_xor(e, 16, 64);
    e += __shfl_xor(e, 32, 64);   // every lane now holds sum of the 16 exps

    if (lane == 0) out[b] = logf(e);
}

extern "C" void kernel_launch(void* const* d_in, const int* in_sizes, int n_in,
                              void* d_out, int out_size, void* d_ws, size_t ws_size,
                              hipStream_t stream) {
    const float* V  = (const float*)d_in[0];
    const float* W  = (const float*)d_in[1];
    const float* vb = (const float*)d_in[2];
    const float* wb = (const float*)d_in[3];
    const unsigned int* IJ = (const unsigned int*)d_in[4];
    float* out = (float*)d_out;

    const int B = out_size;                  // one output per batch element (verified: harness passes)

    // Resolve IJ element width on the host if in_sizes is in bytes:
    // int64 -> B*2*8 bytes, int32 -> B*2*4 bytes. Anything else (e.g. element
    // counts) falls back to the on-device probe (mode 0).
    int mode = 0;
    const long long szIJ = (long long)in_sizes[4];
    if      (szIJ == (long long)B * 16) mode = 1;
    else if (szIJ == (long long)B * 8)  mode = 2;

    const int wavesPerBlock = 4;             // 256 threads
    dim3 block(256);
    dim3 grid((B + wavesPerBlock - 1) / wavesPerBlock);
    hipLaunchKernelGGL(multisense_kernel, grid, block, 0, stream,
                       V, W, vb, wb, IJ, out, B, mode);
}